// Round 11
// baseline (487.108 us; speedup 1.0000x reference)
//
#include <hip/hip_runtime.h>
#include <hip/hip_fp16.h>
#include <math.h>

#define NN 50000
#define EE 640000
#define DD 128
#define LL 3
#define GGR 1024
#define NBLK 196  // 196*256 = 50176 >= NN
#define AGG_BLOCKS 2048

typedef _Float16 half8 __attribute__((ext_vector_type(8)));
typedef float f32x4 __attribute__((ext_vector_type(4)));

// ---------------- CSR build ----------------
__global__ __launch_bounds__(256) void k_hist(const int* __restrict__ dst,
                                              int* __restrict__ cnt) {
  int e = blockIdx.x * 256 + threadIdx.x;
  if (e < EE) atomicAdd(&cnt[dst[e]], 1);
}

__global__ __launch_bounds__(256) void k_scan1(const int* __restrict__ cnt,
                                               int* __restrict__ part) {
  int i = blockIdx.x * 256 + threadIdx.x;
  int v = (i < NN) ? cnt[i] : 0;
  __shared__ int red[256];
  red[threadIdx.x] = v;
  __syncthreads();
  for (int off = 128; off > 0; off >>= 1) {
    if (threadIdx.x < off) red[threadIdx.x] += red[threadIdx.x + off];
    __syncthreads();
  }
  if (threadIdx.x == 0) part[blockIdx.x] = red[0];
}

// scan partials; also zero the 3x256 BN stats region (re-poisoned each call)
__global__ __launch_bounds__(256) void k_scan2(int* __restrict__ part,
                                               float* __restrict__ stats) {
  stats[threadIdx.x] = 0.0f;
  stats[256 + threadIdx.x] = 0.0f;
  stats[512 + threadIdx.x] = 0.0f;
  __shared__ int a[256];
  int t = threadIdx.x;
  int own = (t < NBLK) ? part[t] : 0;
  a[t] = own;
  __syncthreads();
  for (int off = 1; off < 256; off <<= 1) {
    int v = (t >= off) ? a[t - off] : 0;
    __syncthreads();
    a[t] += v;
    __syncthreads();
  }
  if (t < NBLK) part[t] = a[t] - own;  // exclusive
}

__global__ __launch_bounds__(256) void k_scan3(const int* __restrict__ cnt,
                                               const int* __restrict__ part,
                                               int* __restrict__ rowstart,
                                               int* __restrict__ cursor,
                                               float* __restrict__ dinv) {
  int t = threadIdx.x;
  int i = blockIdx.x * 256 + t;
  int c = (i < NN) ? cnt[i] : 0;
  __shared__ int a[256];
  a[t] = c;
  __syncthreads();
  for (int off = 1; off < 256; off <<= 1) {
    int v = (t >= off) ? a[t - off] : 0;
    __syncthreads();
    a[t] += v;
    __syncthreads();
  }
  int excl = a[t] - c + part[blockIdx.x];
  if (i < NN) {
    rowstart[i] = excl;
    cursor[i] = excl;
    dinv[i] = rsqrtf((float)(c + 1));  // +1 self loop
  }
  if (i == 0) rowstart[NN] = EE;
}

__global__ __launch_bounds__(256) void k_scatter(const int* __restrict__ src,
                                                 const int* __restrict__ dst,
                                                 int* __restrict__ cursor,
                                                 int* __restrict__ csr_src) {
  int e = blockIdx.x * 256 + threadIdx.x;
  if (e < EE) {
    int pos = atomicAdd(&cursor[dst[e]], 1);
    csr_src[pos] = src[e];
  }
}

// ---- W prep: transpose + fp16 hi/lo split: Wt[l][col][k] ----
__global__ __launch_bounds__(256) void k_wprep(const float* __restrict__ Ws,
                                               __half* __restrict__ Wth,
                                               __half* __restrict__ Wtl) {
  int i = blockIdx.x * 256 + threadIdx.x;
  if (i >= LL * DD * DD) return;
  int l = i >> 14;  // / (128*128)
  int rem = i & 16383;
  int k = rem >> 7, col = rem & 127;
  float w = Ws[i];
  __half hi = __float2half(w);
  __half lo = __float2half(w - __half2float(hi));
  size_t o = (size_t)l * DD * DD + (size_t)col * DD + k;
  Wth[o] = hi;
  Wtl[o] = lo;
}

// ---------------- GEMM via MFMA (fp16 split precision) ----------------
// Yh[r] = fp16( (dinv[r] * act(X[r])) @ W ).  ACT=0: X is f32 (layer 0).
// ACT=1: X is fp16 (bufAh) and BN scale/shift computed in-kernel from stats.
// LDS tiles XOR-swizzled: byte_in_row ^= ((row&7)<<4) on write AND read.
__device__ __forceinline__ float elu1(float x) {
  return x > 0.0f ? x : expm1f(x);
}

template <int ACT>
__global__ __launch_bounds__(512) void k_gemm(const void* __restrict__ Xin,
                                              const __half* __restrict__ Wth,
                                              const __half* __restrict__ Wtl,
                                              __half* __restrict__ Yh,
                                              const float* __restrict__ stats,
                                              const float* __restrict__ gamma_,
                                              const float* __restrict__ beta_,
                                              const float* __restrict__ dinv) {
  __shared__ __align__(16) __half Wh_s[DD * DD];   // [col][k] hi
  __shared__ __align__(16) __half Wl_s[DD * DD];   // [col][k] lo
  __shared__ __align__(16) __half Xh_s[128 * DD];  // [row][k] hi
  __shared__ __align__(16) __half Xl_s[128 * DD];  // [row][k] lo
  __shared__ float scs[DD], shs[DD];
  const int t = threadIdx.x;
  if (ACT && t < DD) {  // BN finalize (fused, per block)
    float mu = stats[t] * (1.0f / NN);
    float var = stats[DD + t] * (1.0f / NN) - mu * mu;
    float rsig = rsqrtf(var + 1e-5f);
    float sc = gamma_[t] * rsig;
    scs[t] = sc;
    shs[t] = beta_[t] - sc * mu;
  }
  char* WhB = (char*)Wh_s;
  char* WlB = (char*)Wl_s;
  for (int ch = t; ch < DD * DD / 8; ch += 512) {
    int col = ch >> 4;
    int k0 = (ch & 15) << 3;
    half8 h = *reinterpret_cast<const half8*>(Wth + (size_t)col * DD + k0);
    half8 l = *reinterpret_cast<const half8*>(Wtl + (size_t)col * DD + k0);
    int off = col * 256 + ((k0 * 2) ^ ((col & 7) << 4));
    *reinterpret_cast<half8*>(WhB + off) = h;
    *reinterpret_cast<half8*>(WlB + off) = l;
  }
  __syncthreads();  // scs/shs visible before X staging

  const int base = blockIdx.x * 128;
  char* XhB = (char*)Xh_s;
  char* XlB = (char*)Xl_s;
  for (int i = t; i < 128 * 32; i += 512) {
    int rl = i >> 5;
    int r = base + rl;
    int kq = i & 31;
    float4 v = make_float4(0.f, 0.f, 0.f, 0.f);
    float dv = 0.0f;
    if (r < NN) {
      if (ACT) {
        const __half2* X2 = reinterpret_cast<const __half2*>(Xin);
        float2 p0 = __half22float2(X2[(size_t)r * 64 + kq * 2]);
        float2 p1 = __half22float2(X2[(size_t)r * 64 + kq * 2 + 1]);
        v = make_float4(p0.x, p0.y, p1.x, p1.y);
      } else {
        v = reinterpret_cast<const float4*>(Xin)[(size_t)r * 32 + kq];
      }
      dv = dinv[r];
    }
    if (ACT) {
      float4 sc = reinterpret_cast<const float4*>(scs)[kq];
      float4 sh = reinterpret_cast<const float4*>(shs)[kq];
      v.x = elu1(fmaf(v.x, sc.x, sh.x));
      v.y = elu1(fmaf(v.y, sc.y, sh.y));
      v.z = elu1(fmaf(v.z, sc.z, sh.z));
      v.w = elu1(fmaf(v.w, sc.w, sh.w));
    }
    v.x *= dv; v.y *= dv; v.z *= dv; v.w *= dv;
    __half2 h0 = __floats2half2_rn(v.x, v.y);
    __half2 h1 = __floats2half2_rn(v.z, v.w);
    __half2 l0 = __floats2half2_rn(v.x - __low2float(h0), v.y - __high2float(h0));
    __half2 l1 = __floats2half2_rn(v.z - __low2float(h1), v.w - __high2float(h1));
    int off = rl * 256 + ((kq * 8) ^ ((rl & 7) << 4));
    *reinterpret_cast<__half2*>(XhB + off) = h0;
    *reinterpret_cast<__half2*>(XhB + off + 4) = h1;
    *reinterpret_cast<__half2*>(XlB + off) = l0;
    *reinterpret_cast<__half2*>(XlB + off + 4) = l1;
  }
  __syncthreads();

  // fragment layout: A row=lane%16, k=8*(lane/16)+j; B col=lane%16 ([col][k]);
  // D row=4*(lane/16)+j
  const int w = t >> 6, l = t & 63;
  const int lr = l & 15, lg = l >> 4;
  const int arow = w * 16 + lr;
  const int aswz = (arow & 7) << 4;
  f32x4 acc[8];
#pragma unroll
  for (int c = 0; c < 8; ++c) acc[c] = (f32x4){0.f, 0.f, 0.f, 0.f};
#pragma unroll
  for (int kk = 0; kk < 4; ++kk) {
    int kbyte = kk * 64 + lg * 16;
    half8 Ah = *reinterpret_cast<half8*>(XhB + arow * 256 + (kbyte ^ aswz));
    half8 Al = *reinterpret_cast<half8*>(XlB + arow * 256 + (kbyte ^ aswz));
#pragma unroll
    for (int c = 0; c < 8; ++c) {
      int col = c * 16 + lr;
      int boff = col * 256 + (kbyte ^ ((col & 7) << 4));
      half8 Bh = *reinterpret_cast<half8*>(WhB + boff);
      half8 Bl = *reinterpret_cast<half8*>(WlB + boff);
      acc[c] = __builtin_amdgcn_mfma_f32_16x16x32_f16(Ah, Bh, acc[c], 0, 0, 0);
      acc[c] = __builtin_amdgcn_mfma_f32_16x16x32_f16(Al, Bh, acc[c], 0, 0, 0);
      acc[c] = __builtin_amdgcn_mfma_f32_16x16x32_f16(Ah, Bl, acc[c], 0, 0, 0);
    }
  }
#pragma unroll
  for (int c = 0; c < 8; ++c) {
#pragma unroll
    for (int j = 0; j < 4; ++j) {
      int row = base + w * 16 + lg * 4 + j;
      if (row < NN)
        Yh[(size_t)row * DD + c * 16 + lr] = __float2half(acc[c][j]);
    }
  }
}

// ---- CSR aggregation + fused BN stats ----
// outh[d] = fp16( dinv[d]*(Hs[d] + sum Hs[src]) ); per-thread register
// accumulation of sum/sumsq (thread owns feats 2L,2L+1), block-reduced once.
__global__ __launch_bounds__(256) void k_agg_csr(const __half2* __restrict__ Hs,
                                                 const int* __restrict__ rowstart,
                                                 const int* __restrict__ csr_src,
                                                 const float* __restrict__ dinv,
                                                 __half2* __restrict__ outh,
                                                 float* __restrict__ stats) {
  int g = threadIdx.x >> 6;    // 0..3
  int lane = threadIdx.x & 63; // feats 2*lane, 2*lane+1
  float sx = 0.f, sy = 0.f, qx = 0.f, qy = 0.f;
  for (int d = blockIdx.x * 4 + g; d < NN; d += AGG_BLOCKS * 4) {
    int beg = rowstart[d], end = rowstart[d + 1];
    float2 s = __half22float2(Hs[(size_t)d * 64 + lane]);  // self loop
    float a0x = s.x, a0y = s.y;
    float a1x = 0.f, a1y = 0.f, a2x = 0.f, a2y = 0.f, a3x = 0.f, a3y = 0.f;
    int i = beg;
    for (; i + 3 < end; i += 4) {
      int s0 = csr_src[i], s1 = csr_src[i + 1];
      int s2 = csr_src[i + 2], s3 = csr_src[i + 3];
      float2 v0 = __half22float2(Hs[(size_t)s0 * 64 + lane]);
      float2 v1 = __half22float2(Hs[(size_t)s1 * 64 + lane]);
      float2 v2 = __half22float2(Hs[(size_t)s2 * 64 + lane]);
      float2 v3 = __half22float2(Hs[(size_t)s3 * 64 + lane]);
      a0x += v0.x; a0y += v0.y;
      a1x += v1.x; a1y += v1.y;
      a2x += v2.x; a2y += v2.y;
      a3x += v3.x; a3y += v3.y;
    }
    for (; i < end; ++i) {
      float2 v = __half22float2(Hs[(size_t)csr_src[i] * 64 + lane]);
      a0x += v.x; a0y += v.y;
    }
    float dv = dinv[d];
    float rx = (a0x + a1x + a2x + a3x) * dv;
    float ry = (a0y + a1y + a2y + a3y) * dv;
    outh[(size_t)d * 64 + lane] = __floats2half2_rn(rx, ry);
    sx += rx; sy += ry;
    qx = fmaf(rx, rx, qx); qy = fmaf(ry, ry, qy);
  }
  __shared__ float reds[4][128];
  __shared__ float redq[4][128];
  reds[g][2 * lane] = sx; reds[g][2 * lane + 1] = sy;
  redq[g][2 * lane] = qx; redq[g][2 * lane + 1] = qy;
  __syncthreads();
  int t = threadIdx.x;
  if (t < 128) {
    float s = reds[0][t] + reds[1][t] + reds[2][t] + reds[3][t];
    float q = redq[0][t] + redq[1][t] + redq[2][t] + redq[3][t];
    atomicAdd(&stats[t], s);
    atomicAdd(&stats[DD + t], q);
  }
}

// ---- pooling: BN finalize + ELU fused; run-length segmented atomics --------
__global__ __launch_bounds__(256) void k_pool(const __half* __restrict__ H,
                                              const int* __restrict__ bidx,
                                              const float* __restrict__ stats,
                                              const float* __restrict__ gamma_,
                                              const float* __restrict__ beta_,
                                              float* __restrict__ out,
                                              float* __restrict__ cnts) {
  __shared__ float scs[DD], shs[DD];
  int f = threadIdx.x & 127;
  int h = threadIdx.x >> 7;
  if (threadIdx.x < DD) {
    float mu = stats[threadIdx.x] * (1.0f / NN);
    float var = stats[DD + threadIdx.x] * (1.0f / NN) - mu * mu;
    float rsig = rsqrtf(var + 1e-5f);
    float sc = gamma_[threadIdx.x] * rsig;
    scs[threadIdx.x] = sc;
    shs[threadIdx.x] = beta_[threadIdx.x] - sc * mu;
  }
  __syncthreads();
  int n0 = blockIdx.x * 128 + h * 64;
  if (n0 >= NN) return;
  int n1 = min(n0 + 64, NN);
  float sc = scs[f], sh = shs[f];
  int gcur = bidx[n0];
  float racc = 0.0f, rcnt = 0.0f;
  for (int n = n0; n < n1; ++n) {
    int g = bidx[n];
    if (g != gcur) {
      atomicAdd(&out[(size_t)gcur * DD + f], racc);
      if (f == 0) atomicAdd(&cnts[gcur], rcnt);
      gcur = g;
      racc = 0.0f;
      rcnt = 0.0f;
    }
    float v = elu1(fmaf(__half2float(H[(size_t)n * DD + f]), sc, sh));
    racc += v;
    rcnt += 1.0f;
  }
  atomicAdd(&out[(size_t)gcur * DD + f], racc);
  if (f == 0) atomicAdd(&cnts[gcur], rcnt);
}

__global__ __launch_bounds__(256) void k_div(float* __restrict__ out,
                                             const float* __restrict__ cnts) {
  int i = blockIdx.x * 256 + threadIdx.x;
  if (i >= GGR * DD) return;
  out[i] = out[i] / fmaxf(cnts[i >> 7], 1.0f);
}

// ---------------- launch ----------------
extern "C" void kernel_launch(void* const* d_in, const int* in_sizes, int n_in,
                              void* d_out, int out_size, void* d_ws, size_t ws_size,
                              hipStream_t stream) {
  const float* x      = (const float*)d_in[0];
  const float* Ws     = (const float*)d_in[1];
  // d_in[2] = bs: uniform column shift cancels inside BatchNorm -> skipped
  const float* gammas = (const float*)d_in[3];
  const float* betas  = (const float*)d_in[4];
  const int*   ei     = (const int*)d_in[5];
  const int*   bidx   = (const int*)d_in[6];
  const int* srcp = ei;
  const int* dstp = ei + EE;

  __half* Wth  = (__half*)d_ws;                  // 3*128*128 fp16 (hi)
  __half* Wtl  = Wth + (size_t)LL * DD * DD;     // 3*128*128 fp16 (lo)
  __half* bufA = (__half*)(Wtl + (size_t)LL * DD * DD);  // N*128 fp16 (agg out)
  __half* bufB = bufA + (size_t)NN * DD;         // N*128 fp16 (gemm out)
  float* dinv  = (float*)(bufB + (size_t)NN * DD);  // N
  float* stats = dinv + NN;                      // 3*256 (sum, sumsq per layer)
  float* cnts  = stats + 3 * 256;                // G
  int* cnt      = (int*)(cnts + GGR);            // N
  int* rowstart = cnt + NN;                      // N+1
  int* cursor   = rowstart + NN + 1;             // N
  int* csr_src  = cursor + NN;                   // E
  int* part     = csr_src + EE;                  // NBLK
  float* out = (float*)d_out;

  // W transpose + split (once per call)
  k_wprep<<<(LL * DD * DD + 255) / 256, 256, 0, stream>>>(Ws, Wth, Wtl);

  // CSR build (once per call, reused for all 3 layers)
  hipMemsetAsync(cnt, 0, NN * sizeof(int), stream);
  k_hist<<<(EE + 255) / 256, 256, 0, stream>>>(dstp, cnt);
  k_scan1<<<NBLK, 256, 0, stream>>>(cnt, part);
  k_scan2<<<1, 256, 0, stream>>>(part, stats);
  k_scan3<<<NBLK, 256, 0, stream>>>(cnt, part, rowstart, cursor, dinv);
  k_scatter<<<(EE + 255) / 256, 256, 0, stream>>>(srcp, dstp, cursor, csr_src);

  const void* Xin = x;
  for (int l = 0; l < LL; ++l) {
    const __half* Wh = Wth + (size_t)l * DD * DD;
    const __half* Wl = Wtl + (size_t)l * DD * DD;
    if (l == 0)
      k_gemm<0><<<(NN + 127) / 128, 512, 0, stream>>>(
          Xin, Wh, Wl, bufB, stats, gammas, betas, dinv);
    else
      k_gemm<1><<<(NN + 127) / 128, 512, 0, stream>>>(
          Xin, Wh, Wl, bufB, stats + (l - 1) * 256, gammas + (l - 1) * DD,
          betas + (l - 1) * DD, dinv);
    k_agg_csr<<<AGG_BLOCKS, 256, 0, stream>>>((const __half2*)bufB, rowstart,
                                              csr_src, dinv, (__half2*)bufA,
                                              stats + l * 256);
    Xin = bufA;
  }

  hipMemsetAsync(out, 0, (size_t)GGR * DD * sizeof(float), stream);
  hipMemsetAsync(cnts, 0, GGR * sizeof(float), stream);
  k_pool<<<(NN + 127) / 128, 256, 0, stream>>>(bufA, bidx, stats + 2 * 256,
                                               gammas + 2 * DD, betas + 2 * DD,
                                               out, cnts);
  k_div<<<(GGR * DD + 255) / 256, 256, 0, stream>>>(out, cnts);
}

// Round 12
// 391.878 us; speedup vs baseline: 1.2430x; 1.2430x over previous
//
#include <hip/hip_runtime.h>
#include <hip/hip_fp16.h>
#include <math.h>

#define NN 50000
#define EE 640000
#define DD 128
#define LL 3
#define GGR 1024
#define NBLK 196  // 196*256 = 50176 >= NN

typedef _Float16 half8 __attribute__((ext_vector_type(8)));
typedef float f32x4 __attribute__((ext_vector_type(4)));

// ---------------- CSR build ----------------
__global__ __launch_bounds__(256) void k_hist(const int* __restrict__ dst,
                                              int* __restrict__ cnt) {
  int e = blockIdx.x * 256 + threadIdx.x;
  if (e < EE) atomicAdd(&cnt[dst[e]], 1);
}

__global__ __launch_bounds__(256) void k_scan1(const int* __restrict__ cnt,
                                               int* __restrict__ part) {
  int i = blockIdx.x * 256 + threadIdx.x;
  int v = (i < NN) ? cnt[i] : 0;
  __shared__ int red[256];
  red[threadIdx.x] = v;
  __syncthreads();
  for (int off = 128; off > 0; off >>= 1) {
    if (threadIdx.x < off) red[threadIdx.x] += red[threadIdx.x + off];
    __syncthreads();
  }
  if (threadIdx.x == 0) part[blockIdx.x] = red[0];
}

// scan partials; also zero the 3x256 BN stats region (re-poisoned each call)
__global__ __launch_bounds__(256) void k_scan2(int* __restrict__ part,
                                               float* __restrict__ stats) {
  stats[threadIdx.x] = 0.0f;
  stats[256 + threadIdx.x] = 0.0f;
  stats[512 + threadIdx.x] = 0.0f;
  __shared__ int a[256];
  int t = threadIdx.x;
  int own = (t < NBLK) ? part[t] : 0;
  a[t] = own;
  __syncthreads();
  for (int off = 1; off < 256; off <<= 1) {
    int v = (t >= off) ? a[t - off] : 0;
    __syncthreads();
    a[t] += v;
    __syncthreads();
  }
  if (t < NBLK) part[t] = a[t] - own;  // exclusive
}

__global__ __launch_bounds__(256) void k_scan3(const int* __restrict__ cnt,
                                               const int* __restrict__ part,
                                               int* __restrict__ rowstart,
                                               int* __restrict__ cursor,
                                               float* __restrict__ dinv) {
  int t = threadIdx.x;
  int i = blockIdx.x * 256 + t;
  int c = (i < NN) ? cnt[i] : 0;
  __shared__ int a[256];
  a[t] = c;
  __syncthreads();
  for (int off = 1; off < 256; off <<= 1) {
    int v = (t >= off) ? a[t - off] : 0;
    __syncthreads();
    a[t] += v;
    __syncthreads();
  }
  int excl = a[t] - c + part[blockIdx.x];
  if (i < NN) {
    rowstart[i] = excl;
    cursor[i] = excl;
    dinv[i] = rsqrtf((float)(c + 1));  // +1 self loop
  }
  if (i == 0) rowstart[NN] = EE;
}

__global__ __launch_bounds__(256) void k_scatter(const int* __restrict__ src,
                                                 const int* __restrict__ dst,
                                                 int* __restrict__ cursor,
                                                 int* __restrict__ csr_src) {
  int e = blockIdx.x * 256 + threadIdx.x;
  if (e < EE) {
    int pos = atomicAdd(&cursor[dst[e]], 1);
    csr_src[pos] = src[e];
  }
}

// ---- W prep: transpose + fp16 hi/lo split: Wt[l][col][k] ----
__global__ __launch_bounds__(256) void k_wprep(const float* __restrict__ Ws,
                                               __half* __restrict__ Wth,
                                               __half* __restrict__ Wtl) {
  int i = blockIdx.x * 256 + threadIdx.x;
  if (i >= LL * DD * DD) return;
  int l = i >> 14;  // / (128*128)
  int rem = i & 16383;
  int k = rem >> 7, col = rem & 127;
  float w = Ws[i];
  __half hi = __float2half(w);
  __half lo = __float2half(w - __half2float(hi));
  size_t o = (size_t)l * DD * DD + (size_t)col * DD + k;
  Wth[o] = hi;
  Wtl[o] = lo;
}

// ---------------- GEMM via MFMA (fp16 split precision) ----------------
// Yh[r] = fp16( (dinv[r] * act(X[r])) @ W ).  ACT=0: X is f32 (layer 0).
// ACT=1: X is fp16 (bufA) and BN scale/shift computed in-kernel from stats.
// LDS tiles XOR-swizzled: byte_in_row ^= ((row&7)<<4) on write AND read.
__device__ __forceinline__ float elu1(float x) {
  return x > 0.0f ? x : expm1f(x);
}

template <int ACT>
__global__ __launch_bounds__(512) void k_gemm(const void* __restrict__ Xin,
                                              const __half* __restrict__ Wth,
                                              const __half* __restrict__ Wtl,
                                              __half* __restrict__ Yh,
                                              const float* __restrict__ stats,
                                              const float* __restrict__ gamma_,
                                              const float* __restrict__ beta_,
                                              const float* __restrict__ dinv) {
  __shared__ __align__(16) __half Wh_s[DD * DD];   // [col][k] hi
  __shared__ __align__(16) __half Wl_s[DD * DD];   // [col][k] lo
  __shared__ __align__(16) __half Xh_s[128 * DD];  // [row][k] hi
  __shared__ __align__(16) __half Xl_s[128 * DD];  // [row][k] lo
  __shared__ float scs[DD], shs[DD];
  const int t = threadIdx.x;
  if (ACT && t < DD) {  // BN finalize (fused, per block)
    float mu = stats[t] * (1.0f / NN);
    float var = stats[DD + t] * (1.0f / NN) - mu * mu;
    float rsig = rsqrtf(var + 1e-5f);
    float sc = gamma_[t] * rsig;
    scs[t] = sc;
    shs[t] = beta_[t] - sc * mu;
  }
  char* WhB = (char*)Wh_s;
  char* WlB = (char*)Wl_s;
  for (int ch = t; ch < DD * DD / 8; ch += 512) {
    int col = ch >> 4;
    int k0 = (ch & 15) << 3;
    half8 h = *reinterpret_cast<const half8*>(Wth + (size_t)col * DD + k0);
    half8 l = *reinterpret_cast<const half8*>(Wtl + (size_t)col * DD + k0);
    int off = col * 256 + ((k0 * 2) ^ ((col & 7) << 4));
    *reinterpret_cast<half8*>(WhB + off) = h;
    *reinterpret_cast<half8*>(WlB + off) = l;
  }
  __syncthreads();  // scs/shs visible before X staging

  const int base = blockIdx.x * 128;
  char* XhB = (char*)Xh_s;
  char* XlB = (char*)Xl_s;
  for (int i = t; i < 128 * 32; i += 512) {
    int rl = i >> 5;
    int r = base + rl;
    int kq = i & 31;
    float4 v = make_float4(0.f, 0.f, 0.f, 0.f);
    float dv = 0.0f;
    if (r < NN) {
      if (ACT) {
        const __half2* X2 = reinterpret_cast<const __half2*>(Xin);
        float2 p0 = __half22float2(X2[(size_t)r * 64 + kq * 2]);
        float2 p1 = __half22float2(X2[(size_t)r * 64 + kq * 2 + 1]);
        v = make_float4(p0.x, p0.y, p1.x, p1.y);
      } else {
        v = reinterpret_cast<const float4*>(Xin)[(size_t)r * 32 + kq];
      }
      dv = dinv[r];
    }
    if (ACT) {
      float4 sc = reinterpret_cast<const float4*>(scs)[kq];
      float4 sh = reinterpret_cast<const float4*>(shs)[kq];
      v.x = elu1(fmaf(v.x, sc.x, sh.x));
      v.y = elu1(fmaf(v.y, sc.y, sh.y));
      v.z = elu1(fmaf(v.z, sc.z, sh.z));
      v.w = elu1(fmaf(v.w, sc.w, sh.w));
    }
    v.x *= dv; v.y *= dv; v.z *= dv; v.w *= dv;
    __half2 h0 = __floats2half2_rn(v.x, v.y);
    __half2 h1 = __floats2half2_rn(v.z, v.w);
    __half2 l0 = __floats2half2_rn(v.x - __low2float(h0), v.y - __high2float(h0));
    __half2 l1 = __floats2half2_rn(v.z - __low2float(h1), v.w - __high2float(h1));
    int off = rl * 256 + ((kq * 8) ^ ((rl & 7) << 4));
    *reinterpret_cast<__half2*>(XhB + off) = h0;
    *reinterpret_cast<__half2*>(XhB + off + 4) = h1;
    *reinterpret_cast<__half2*>(XlB + off) = l0;
    *reinterpret_cast<__half2*>(XlB + off + 4) = l1;
  }
  __syncthreads();

  // fragment layout: A row=lane%16, k=8*(lane/16)+j; B col=lane%16 ([col][k]);
  // D row=4*(lane/16)+j
  const int w = t >> 6, l = t & 63;
  const int lr = l & 15, lg = l >> 4;
  const int arow = w * 16 + lr;
  const int aswz = (arow & 7) << 4;
  f32x4 acc[8];
#pragma unroll
  for (int c = 0; c < 8; ++c) acc[c] = (f32x4){0.f, 0.f, 0.f, 0.f};
#pragma unroll
  for (int kk = 0; kk < 4; ++kk) {
    int kbyte = kk * 64 + lg * 16;
    half8 Ah = *reinterpret_cast<half8*>(XhB + arow * 256 + (kbyte ^ aswz));
    half8 Al = *reinterpret_cast<half8*>(XlB + arow * 256 + (kbyte ^ aswz));
#pragma unroll
    for (int c = 0; c < 8; ++c) {
      int col = c * 16 + lr;
      int boff = col * 256 + (kbyte ^ ((col & 7) << 4));
      half8 Bh = *reinterpret_cast<half8*>(WhB + boff);
      half8 Bl = *reinterpret_cast<half8*>(WlB + boff);
      acc[c] = __builtin_amdgcn_mfma_f32_16x16x32_f16(Ah, Bh, acc[c], 0, 0, 0);
      acc[c] = __builtin_amdgcn_mfma_f32_16x16x32_f16(Al, Bh, acc[c], 0, 0, 0);
      acc[c] = __builtin_amdgcn_mfma_f32_16x16x32_f16(Ah, Bl, acc[c], 0, 0, 0);
    }
  }
#pragma unroll
  for (int c = 0; c < 8; ++c) {
#pragma unroll
    for (int j = 0; j < 4; ++j) {
      int row = base + w * 16 + lg * 4 + j;
      if (row < NN)
        Yh[(size_t)row * DD + c * 16 + lr] = __float2half(acc[c][j]);
    }
  }
}

// ---- CSR aggregation: outh[d] = fp16( dinv[d]*(Hs[d] + sum Hs[src]) ) -----
// one row per 64-lane group, 4 rows/block, 8-deep batches with min-clamped
// indices + predicated accumulate (1 waitcnt per 8 gathers, no branchy tail)
__global__ __launch_bounds__(256) void k_agg_csr(const __half2* __restrict__ Hs,
                                                 const int* __restrict__ rowstart,
                                                 const int* __restrict__ csr_src,
                                                 const float* __restrict__ dinv,
                                                 __half2* __restrict__ outh) {
  int d = blockIdx.x * 4 + (threadIdx.x >> 6);
  if (d >= NN) return;
  int lane = threadIdx.x & 63;
  int beg = rowstart[d], end = rowstart[d + 1];

  float2 s = __half22float2(Hs[(size_t)d * 64 + lane]);  // self loop
  float ax0 = s.x, ay0 = s.y;
  float ax1 = 0.f, ay1 = 0.f, ax2 = 0.f, ay2 = 0.f, ax3 = 0.f, ay3 = 0.f;

  for (int i = beg; i < end; i += 8) {
    float2 v[8];
#pragma unroll
    for (int j = 0; j < 8; ++j) {
      int sj = csr_src[min(i + j, end - 1)];
      v[j] = __half22float2(Hs[(size_t)sj * 64 + lane]);
    }
#pragma unroll
    for (int j = 0; j < 8; ++j) {
      bool ok = (i + j < end);
      float wx = ok ? v[j].x : 0.f;
      float wy = ok ? v[j].y : 0.f;
      switch (j & 3) {
        case 0: ax0 += wx; ay0 += wy; break;
        case 1: ax1 += wx; ay1 += wy; break;
        case 2: ax2 += wx; ay2 += wy; break;
        default: ax3 += wx; ay3 += wy; break;
      }
    }
  }
  float dv = dinv[d];
  float rx = (ax0 + ax1 + ax2 + ax3) * dv;
  float ry = (ay0 + ay1 + ay2 + ay3) * dv;
  outh[(size_t)d * 64 + lane] = __floats2half2_rn(rx, ry);
}

// ---------------- BatchNorm stats (fp16 input, standalone) ----------------
__global__ __launch_bounds__(256) void k_bnstats(const __half2* __restrict__ H,
                                                 float* __restrict__ stats) {
  int g = threadIdx.x >> 6;     // 0..3
  int lane = threadIdx.x & 63;  // feats 2*lane, 2*lane+1
  float sx = 0.f, sy = 0.f, qx = 0.f, qy = 0.f;
  for (int r = blockIdx.x * 4 + g; r < NN; r += 256 * 4) {
    float2 v = __half22float2(H[(size_t)r * 64 + lane]);
    sx += v.x; sy += v.y;
    qx = fmaf(v.x, v.x, qx);
    qy = fmaf(v.y, v.y, qy);
  }
  __shared__ float reds[4][128];
  __shared__ float redq[4][128];
  reds[g][2 * lane] = sx; reds[g][2 * lane + 1] = sy;
  redq[g][2 * lane] = qx; redq[g][2 * lane + 1] = qy;
  __syncthreads();
  int t = threadIdx.x;
  if (t < 128) {
    float s = reds[0][t] + reds[1][t] + reds[2][t] + reds[3][t];
    float q = redq[0][t] + redq[1][t] + redq[2][t] + redq[3][t];
    atomicAdd(&stats[t], s);
    atomicAdd(&stats[DD + t], q);
  }
}

// ---- pooling: BN finalize + ELU fused; run-length segmented atomics --------
__global__ __launch_bounds__(256) void k_pool(const __half* __restrict__ H,
                                              const int* __restrict__ bidx,
                                              const float* __restrict__ stats,
                                              const float* __restrict__ gamma_,
                                              const float* __restrict__ beta_,
                                              float* __restrict__ out,
                                              float* __restrict__ cnts) {
  __shared__ float scs[DD], shs[DD];
  int f = threadIdx.x & 127;
  int h = threadIdx.x >> 7;
  if (threadIdx.x < DD) {
    float mu = stats[threadIdx.x] * (1.0f / NN);
    float var = stats[DD + threadIdx.x] * (1.0f / NN) - mu * mu;
    float rsig = rsqrtf(var + 1e-5f);
    float sc = gamma_[threadIdx.x] * rsig;
    scs[threadIdx.x] = sc;
    shs[threadIdx.x] = beta_[threadIdx.x] - sc * mu;
  }
  __syncthreads();
  int n0 = blockIdx.x * 128 + h * 64;
  if (n0 >= NN) return;
  int n1 = min(n0 + 64, NN);
  float sc = scs[f], sh = shs[f];
  int gcur = bidx[n0];
  float racc = 0.0f, rcnt = 0.0f;
  for (int n = n0; n < n1; ++n) {
    int g = bidx[n];
    if (g != gcur) {
      atomicAdd(&out[(size_t)gcur * DD + f], racc);
      if (f == 0) atomicAdd(&cnts[gcur], rcnt);
      gcur = g;
      racc = 0.0f;
      rcnt = 0.0f;
    }
    float v = elu1(fmaf(__half2float(H[(size_t)n * DD + f]), sc, sh));
    racc += v;
    rcnt += 1.0f;
  }
  atomicAdd(&out[(size_t)gcur * DD + f], racc);
  if (f == 0) atomicAdd(&cnts[gcur], rcnt);
}

__global__ __launch_bounds__(256) void k_div(float* __restrict__ out,
                                             const float* __restrict__ cnts) {
  int i = blockIdx.x * 256 + threadIdx.x;
  if (i >= GGR * DD) return;
  out[i] = out[i] / fmaxf(cnts[i >> 7], 1.0f);
}

// ---------------- launch ----------------
extern "C" void kernel_launch(void* const* d_in, const int* in_sizes, int n_in,
                              void* d_out, int out_size, void* d_ws, size_t ws_size,
                              hipStream_t stream) {
  const float* x      = (const float*)d_in[0];
  const float* Ws     = (const float*)d_in[1];
  // d_in[2] = bs: uniform column shift cancels inside BatchNorm -> skipped
  const float* gammas = (const float*)d_in[3];
  const float* betas  = (const float*)d_in[4];
  const int*   ei     = (const int*)d_in[5];
  const int*   bidx   = (const int*)d_in[6];
  const int* srcp = ei;
  const int* dstp = ei + EE;

  __half* Wth  = (__half*)d_ws;                  // 3*128*128 fp16 (hi)
  __half* Wtl  = Wth + (size_t)LL * DD * DD;     // 3*128*128 fp16 (lo)
  __half* bufA = (__half*)(Wtl + (size_t)LL * DD * DD);  // N*128 fp16 (agg out)
  __half* bufB = bufA + (size_t)NN * DD;         // N*128 fp16 (gemm out)
  float* dinv  = (float*)(bufB + (size_t)NN * DD);  // N
  float* stats = dinv + NN;                      // 3*256 (sum, sumsq per layer)
  float* cnts  = stats + 3 * 256;                // G
  int* cnt      = (int*)(cnts + GGR);            // N
  int* rowstart = cnt + NN;                      // N+1
  int* cursor   = rowstart + NN + 1;             // N
  int* csr_src  = cursor + NN;                   // E
  int* part     = csr_src + EE;                  // NBLK
  float* out = (float*)d_out;

  // W transpose + split (once per call)
  k_wprep<<<(LL * DD * DD + 255) / 256, 256, 0, stream>>>(Ws, Wth, Wtl);

  // CSR build (once per call, reused for all 3 layers)
  hipMemsetAsync(cnt, 0, NN * sizeof(int), stream);
  k_hist<<<(EE + 255) / 256, 256, 0, stream>>>(dstp, cnt);
  k_scan1<<<NBLK, 256, 0, stream>>>(cnt, part);
  k_scan2<<<1, 256, 0, stream>>>(part, stats);
  k_scan3<<<NBLK, 256, 0, stream>>>(cnt, part, rowstart, cursor, dinv);
  k_scatter<<<(EE + 255) / 256, 256, 0, stream>>>(srcp, dstp, cursor, csr_src);

  const void* Xin = x;
  for (int l = 0; l < LL; ++l) {
    const __half* Wh = Wth + (size_t)l * DD * DD;
    const __half* Wl = Wtl + (size_t)l * DD * DD;
    if (l == 0)
      k_gemm<0><<<(NN + 127) / 128, 512, 0, stream>>>(
          Xin, Wh, Wl, bufB, stats, gammas, betas, dinv);
    else
      k_gemm<1><<<(NN + 127) / 128, 512, 0, stream>>>(
          Xin, Wh, Wl, bufB, stats + (l - 1) * 256, gammas + (l - 1) * DD,
          betas + (l - 1) * DD, dinv);
    k_agg_csr<<<(NN + 3) / 4, 256, 0, stream>>>((const __half2*)bufB, rowstart,
                                                csr_src, dinv, (__half2*)bufA);
    k_bnstats<<<256, 256, 0, stream>>>((const __half2*)bufA, stats + l * 256);
    Xin = bufA;
  }

  hipMemsetAsync(out, 0, (size_t)GGR * DD * sizeof(float), stream);
  hipMemsetAsync(cnts, 0, GGR * sizeof(float), stream);
  k_pool<<<(NN + 127) / 128, 256, 0, stream>>>(bufA, bidx, stats + 2 * 256,
                                               gammas + 2 * DD, betas + 2 * DD,
                                               out, cnts);
  k_div<<<(GGR * DD + 255) / 256, 256, 0, stream>>>(out, cnts);
}

// Round 13
// 366.125 us; speedup vs baseline: 1.3304x; 1.0703x over previous
//
#include <hip/hip_runtime.h>
#include <hip/hip_fp16.h>
#include <math.h>

#define NN 50000
#define EE 640000
#define DD 128
#define LL 3
#define GGR 1024
#define NBLK 196  // 196*256 = 50176 >= NN

typedef _Float16 half8 __attribute__((ext_vector_type(8)));
typedef float f32x4 __attribute__((ext_vector_type(4)));

// ---- fused W-prep (blocks 0..191) + degree histogram (blocks 192..) ----
__global__ __launch_bounds__(256) void k_prep(const float* __restrict__ Ws,
                                              __half* __restrict__ Wth,
                                              __half* __restrict__ Wtl,
                                              const int* __restrict__ dst,
                                              int* __restrict__ cnt) {
  int b = blockIdx.x;
  if (b < 192) {  // 192*256 = 49152 = LL*DD*DD : transpose + fp16 hi/lo split
    int i = b * 256 + threadIdx.x;
    int l = i >> 14;
    int rem = i & 16383;
    int k = rem >> 7, col = rem & 127;
    float w = Ws[i];
    __half hi = __float2half(w);
    __half lo = __float2half(w - __half2float(hi));
    size_t o = (size_t)l * DD * DD + (size_t)col * DD + k;
    Wth[o] = hi;
    Wtl[o] = lo;
  } else {
    int e = (b - 192) * 256 + threadIdx.x;
    if (e < EE) atomicAdd(&cnt[dst[e]], 1);
  }
}

// pass 1 — per-block sums; also zeroes pool accumulators (re-poisoned)
__global__ __launch_bounds__(256) void k_scan1(const int* __restrict__ cnt,
                                               int* __restrict__ part,
                                               float* __restrict__ out,
                                               float* __restrict__ cnts) {
  for (int i = blockIdx.x * 256 + threadIdx.x; i < GGR * DD + GGR;
       i += NBLK * 256) {
    if (i < GGR * DD) out[i] = 0.0f;
    else cnts[i - GGR * DD] = 0.0f;
  }
  int i = blockIdx.x * 256 + threadIdx.x;
  int v = (i < NN) ? cnt[i] : 0;
  __shared__ int red[256];
  red[threadIdx.x] = v;
  __syncthreads();
  for (int off = 128; off > 0; off >>= 1) {
    if (threadIdx.x < off) red[threadIdx.x] += red[threadIdx.x + off];
    __syncthreads();
  }
  if (threadIdx.x == 0) part[blockIdx.x] = red[0];
}

// scan partials; also zero the 3x256 BN stats region (re-poisoned each call)
__global__ __launch_bounds__(256) void k_scan2(int* __restrict__ part,
                                               float* __restrict__ stats) {
  stats[threadIdx.x] = 0.0f;
  stats[256 + threadIdx.x] = 0.0f;
  stats[512 + threadIdx.x] = 0.0f;
  __shared__ int a[256];
  int t = threadIdx.x;
  int own = (t < NBLK) ? part[t] : 0;
  a[t] = own;
  __syncthreads();
  for (int off = 1; off < 256; off <<= 1) {
    int v = (t >= off) ? a[t - off] : 0;
    __syncthreads();
    a[t] += v;
    __syncthreads();
  }
  if (t < NBLK) part[t] = a[t] - own;  // exclusive
}

__global__ __launch_bounds__(256) void k_scan3(const int* __restrict__ cnt,
                                               const int* __restrict__ part,
                                               int* __restrict__ rowstart,
                                               int* __restrict__ cursor,
                                               float* __restrict__ dinv) {
  int t = threadIdx.x;
  int i = blockIdx.x * 256 + t;
  int c = (i < NN) ? cnt[i] : 0;
  __shared__ int a[256];
  a[t] = c;
  __syncthreads();
  for (int off = 1; off < 256; off <<= 1) {
    int v = (t >= off) ? a[t - off] : 0;
    __syncthreads();
    a[t] += v;
    __syncthreads();
  }
  int excl = a[t] - c + part[blockIdx.x];
  if (i < NN) {
    rowstart[i] = excl;
    cursor[i] = excl;
    dinv[i] = rsqrtf((float)(c + 1));  // +1 self loop
  }
  if (i == 0) rowstart[NN] = EE;
}

__global__ __launch_bounds__(256) void k_scatter(const int* __restrict__ src,
                                                 const int* __restrict__ dst,
                                                 int* __restrict__ cursor,
                                                 int* __restrict__ csr_src) {
  int e = blockIdx.x * 256 + threadIdx.x;
  if (e < EE) {
    int pos = atomicAdd(&cursor[dst[e]], 1);
    csr_src[pos] = src[e];
  }
}

// ---------------- GEMM via MFMA (fp16 split precision) ----------------
// Yh[r] = fp16( (dinv[r] * act(X[r])) @ W ).  ACT=0: X f32 (layer 0);
// ACT=1: X fp16 + BN finalize in-kernel. W (hi+lo) in LDS, XOR-swizzled;
// A-fragments built directly from global (X read exactly once per block,
// L3-resident) — no X staging, one barrier, 64KB LDS -> 2 blocks/CU.
__device__ __forceinline__ float elu1(float x) {
  return x > 0.0f ? x : expm1f(x);
}

template <int ACT>
__global__ __launch_bounds__(512) void k_gemm(const void* __restrict__ Xin,
                                              const __half* __restrict__ Wth,
                                              const __half* __restrict__ Wtl,
                                              __half* __restrict__ Yh,
                                              const float* __restrict__ stats,
                                              const float* __restrict__ gamma_,
                                              const float* __restrict__ beta_,
                                              const float* __restrict__ dinv) {
  __shared__ __align__(16) __half Wh_s[DD * DD];  // [col][k] hi, swizzled
  __shared__ __align__(16) __half Wl_s[DD * DD];  // [col][k] lo, swizzled
  __shared__ float scs[DD], shs[DD];
  const int t = threadIdx.x;
  if (ACT && t < DD) {  // BN finalize (fused, per block)
    float mu = stats[t] * (1.0f / NN);
    float var = stats[DD + t] * (1.0f / NN) - mu * mu;
    float rsig = rsqrtf(var + 1e-5f);
    float sc = gamma_[t] * rsig;
    scs[t] = sc;
    shs[t] = beta_[t] - sc * mu;
  }
  char* WhB = (char*)Wh_s;
  char* WlB = (char*)Wl_s;
  for (int ch = t; ch < DD * 16; ch += 512) {
    int col = ch >> 4;
    int k0 = (ch & 15) << 3;
    half8 h = *reinterpret_cast<const half8*>(Wth + (size_t)col * DD + k0);
    half8 l = *reinterpret_cast<const half8*>(Wtl + (size_t)col * DD + k0);
    int off = col * 256 + ((k0 * 2) ^ ((col & 7) << 4));
    *reinterpret_cast<half8*>(WhB + off) = h;
    *reinterpret_cast<half8*>(WlB + off) = l;
  }
  __syncthreads();

  // fragment layout: A row=lane%16, k=8*(lane/16)+j (within 32-k step);
  // B col=lane%16 ([col][k]); D row=4*(lane/16)+j
  const int base = blockIdx.x * 128;
  const int w = t >> 6, l = t & 63;
  const int lr = l & 15, lg = l >> 4;
  const int grow = base + w * 16 + lr;
  const bool rok = grow < NN;
  const int growc = rok ? grow : NN - 1;
  const float dv = rok ? dinv[growc] : 0.0f;

  f32x4 acc[8];
#pragma unroll
  for (int c = 0; c < 8; ++c) acc[c] = (f32x4){0.f, 0.f, 0.f, 0.f};

#pragma unroll
  for (int kk = 0; kk < 4; ++kk) {
    const int kbase = kk * 32 + lg * 8;  // first k-half of this fragment
    float xv[8];
    if (ACT) {
      half8 raw = *reinterpret_cast<const half8*>(
          (const __half*)Xin + (size_t)growc * DD + kbase);
#pragma unroll
      for (int j = 0; j < 8; ++j) xv[j] = (float)raw[j];
      float4 sc0 = *reinterpret_cast<const float4*>(&scs[kbase]);
      float4 sc1 = *reinterpret_cast<const float4*>(&scs[kbase + 4]);
      float4 sh0 = *reinterpret_cast<const float4*>(&shs[kbase]);
      float4 sh1 = *reinterpret_cast<const float4*>(&shs[kbase + 4]);
      xv[0] = elu1(fmaf(xv[0], sc0.x, sh0.x));
      xv[1] = elu1(fmaf(xv[1], sc0.y, sh0.y));
      xv[2] = elu1(fmaf(xv[2], sc0.z, sh0.z));
      xv[3] = elu1(fmaf(xv[3], sc0.w, sh0.w));
      xv[4] = elu1(fmaf(xv[4], sc1.x, sh1.x));
      xv[5] = elu1(fmaf(xv[5], sc1.y, sh1.y));
      xv[6] = elu1(fmaf(xv[6], sc1.z, sh1.z));
      xv[7] = elu1(fmaf(xv[7], sc1.w, sh1.w));
    } else {
      const float4* Xf = reinterpret_cast<const float4*>(Xin);
      float4 a = Xf[(size_t)growc * 32 + (kbase >> 2)];
      float4 b = Xf[(size_t)growc * 32 + (kbase >> 2) + 1];
      xv[0] = a.x; xv[1] = a.y; xv[2] = a.z; xv[3] = a.w;
      xv[4] = b.x; xv[5] = b.y; xv[6] = b.z; xv[7] = b.w;
    }
    half8 Ah, Al;
#pragma unroll
    for (int j = 0; j < 8; ++j) {
      float s = xv[j] * dv;
      _Float16 h = (_Float16)s;
      Ah[j] = h;
      Al[j] = (_Float16)(s - (float)h);
    }
    const int kbyte = kk * 64 + lg * 16;
#pragma unroll
    for (int c = 0; c < 8; ++c) {
      int col = c * 16 + lr;
      int boff = col * 256 + (kbyte ^ ((col & 7) << 4));
      half8 Bh = *reinterpret_cast<half8*>(WhB + boff);
      half8 Bl = *reinterpret_cast<half8*>(WlB + boff);
      acc[c] = __builtin_amdgcn_mfma_f32_16x16x32_f16(Ah, Bh, acc[c], 0, 0, 0);
      acc[c] = __builtin_amdgcn_mfma_f32_16x16x32_f16(Al, Bh, acc[c], 0, 0, 0);
      acc[c] = __builtin_amdgcn_mfma_f32_16x16x32_f16(Ah, Bl, acc[c], 0, 0, 0);
    }
  }
#pragma unroll
  for (int c = 0; c < 8; ++c) {
#pragma unroll
    for (int j = 0; j < 4; ++j) {
      int row = base + w * 16 + lg * 4 + j;
      if (row < NN)
        Yh[(size_t)row * DD + c * 16 + lr] = __float2half(acc[c][j]);
    }
  }
}

// ---- CSR aggregation: outh[d] = fp16( dinv[d]*(Hs[d] + sum Hs[src]) ) -----
__global__ __launch_bounds__(256) void k_agg_csr(const __half2* __restrict__ Hs,
                                                 const int* __restrict__ rowstart,
                                                 const int* __restrict__ csr_src,
                                                 const float* __restrict__ dinv,
                                                 __half2* __restrict__ outh) {
  int d = blockIdx.x * 4 + (threadIdx.x >> 6);
  if (d >= NN) return;
  int lane = threadIdx.x & 63;
  int beg = rowstart[d], end = rowstart[d + 1];

  float2 s = __half22float2(Hs[(size_t)d * 64 + lane]);  // self loop
  float ax0 = s.x, ay0 = s.y;
  float ax1 = 0.f, ay1 = 0.f, ax2 = 0.f, ay2 = 0.f, ax3 = 0.f, ay3 = 0.f;

  for (int i = beg; i < end; i += 8) {
    float2 v[8];
#pragma unroll
    for (int j = 0; j < 8; ++j) {
      int sj = csr_src[min(i + j, end - 1)];
      v[j] = __half22float2(Hs[(size_t)sj * 64 + lane]);
    }
#pragma unroll
    for (int j = 0; j < 8; ++j) {
      bool ok = (i + j < end);
      float wx = ok ? v[j].x : 0.f;
      float wy = ok ? v[j].y : 0.f;
      switch (j & 3) {
        case 0: ax0 += wx; ay0 += wy; break;
        case 1: ax1 += wx; ay1 += wy; break;
        case 2: ax2 += wx; ay2 += wy; break;
        default: ax3 += wx; ay3 += wy; break;
      }
    }
  }
  float dv = dinv[d];
  float rx = (ax0 + ax1 + ax2 + ax3) * dv;
  float ry = (ay0 + ay1 + ay2 + ay3) * dv;
  outh[(size_t)d * 64 + lane] = __floats2half2_rn(rx, ry);
}

// ---------------- BatchNorm stats (fp16 input, standalone) ----------------
__global__ __launch_bounds__(256) void k_bnstats(const __half2* __restrict__ H,
                                                 float* __restrict__ stats) {
  int g = threadIdx.x >> 6;     // 0..3
  int lane = threadIdx.x & 63;  // feats 2*lane, 2*lane+1
  float sx = 0.f, sy = 0.f, qx = 0.f, qy = 0.f;
  for (int r = blockIdx.x * 4 + g; r < NN; r += 256 * 4) {
    float2 v = __half22float2(H[(size_t)r * 64 + lane]);
    sx += v.x; sy += v.y;
    qx = fmaf(v.x, v.x, qx);
    qy = fmaf(v.y, v.y, qy);
  }
  __shared__ float reds[4][128];
  __shared__ float redq[4][128];
  reds[g][2 * lane] = sx; reds[g][2 * lane + 1] = sy;
  redq[g][2 * lane] = qx; redq[g][2 * lane + 1] = qy;
  __syncthreads();
  int t = threadIdx.x;
  if (t < 128) {
    float s = reds[0][t] + reds[1][t] + reds[2][t] + reds[3][t];
    float q = redq[0][t] + redq[1][t] + redq[2][t] + redq[3][t];
    atomicAdd(&stats[t], s);
    atomicAdd(&stats[DD + t], q);
  }
}

// ---- pooling: BN finalize + ELU fused; run-length segmented atomics --------
__global__ __launch_bounds__(256) void k_pool(const __half* __restrict__ H,
                                              const int* __restrict__ bidx,
                                              const float* __restrict__ stats,
                                              const float* __restrict__ gamma_,
                                              const float* __restrict__ beta_,
                                              float* __restrict__ out,
                                              float* __restrict__ cnts) {
  __shared__ float scs[DD], shs[DD];
  int f = threadIdx.x & 127;
  int h = threadIdx.x >> 7;
  if (threadIdx.x < DD) {
    float mu = stats[threadIdx.x] * (1.0f / NN);
    float var = stats[DD + threadIdx.x] * (1.0f / NN) - mu * mu;
    float rsig = rsqrtf(var + 1e-5f);
    float sc = gamma_[threadIdx.x] * rsig;
    scs[threadIdx.x] = sc;
    shs[threadIdx.x] = beta_[threadIdx.x] - sc * mu;
  }
  __syncthreads();
  int n0 = blockIdx.x * 128 + h * 64;
  if (n0 >= NN) return;
  int n1 = min(n0 + 64, NN);
  float sc = scs[f], sh = shs[f];
  int gcur = bidx[n0];
  float racc = 0.0f, rcnt = 0.0f;
  for (int n = n0; n < n1; ++n) {
    int g = bidx[n];
    if (g != gcur) {
      atomicAdd(&out[(size_t)gcur * DD + f], racc);
      if (f == 0) atomicAdd(&cnts[gcur], rcnt);
      gcur = g;
      racc = 0.0f;
      rcnt = 0.0f;
    }
    float v = elu1(fmaf(__half2float(H[(size_t)n * DD + f]), sc, sh));
    racc += v;
    rcnt += 1.0f;
  }
  atomicAdd(&out[(size_t)gcur * DD + f], racc);
  if (f == 0) atomicAdd(&cnts[gcur], rcnt);
}

__global__ __launch_bounds__(256) void k_div(float* __restrict__ out,
                                             const float* __restrict__ cnts) {
  int i = blockIdx.x * 256 + threadIdx.x;
  if (i >= GGR * DD) return;
  out[i] = out[i] / fmaxf(cnts[i >> 7], 1.0f);
}

// ---------------- launch ----------------
extern "C" void kernel_launch(void* const* d_in, const int* in_sizes, int n_in,
                              void* d_out, int out_size, void* d_ws, size_t ws_size,
                              hipStream_t stream) {
  const float* x      = (const float*)d_in[0];
  const float* Ws     = (const float*)d_in[1];
  // d_in[2] = bs: uniform column shift cancels inside BatchNorm -> skipped
  const float* gammas = (const float*)d_in[3];
  const float* betas  = (const float*)d_in[4];
  const int*   ei     = (const int*)d_in[5];
  const int*   bidx   = (const int*)d_in[6];
  const int* srcp = ei;
  const int* dstp = ei + EE;

  __half* Wth  = (__half*)d_ws;                  // 3*128*128 fp16 (hi)
  __half* Wtl  = Wth + (size_t)LL * DD * DD;     // 3*128*128 fp16 (lo)
  __half* bufA = (__half*)(Wtl + (size_t)LL * DD * DD);  // N*128 fp16 (agg out)
  __half* bufB = bufA + (size_t)NN * DD;         // N*128 fp16 (gemm out)
  float* dinv  = (float*)(bufB + (size_t)NN * DD);  // N
  float* stats = dinv + NN;                      // 3*256 (sum, sumsq per layer)
  float* cnts  = stats + 3 * 256;                // G
  int* cnt      = (int*)(cnts + GGR);            // N
  int* rowstart = cnt + NN;                      // N+1
  int* cursor   = rowstart + NN + 1;             // N
  int* csr_src  = cursor + NN;                   // E
  int* part     = csr_src + EE;                  // NBLK
  float* out = (float*)d_out;

  // W prep + CSR build (once per call, reused for all 3 layers)
  hipMemsetAsync(cnt, 0, NN * sizeof(int), stream);
  k_prep<<<192 + (EE + 255) / 256, 256, 0, stream>>>(Ws, Wth, Wtl, dstp, cnt);
  k_scan1<<<NBLK, 256, 0, stream>>>(cnt, part, out, cnts);
  k_scan2<<<1, 256, 0, stream>>>(part, stats);
  k_scan3<<<NBLK, 256, 0, stream>>>(cnt, part, rowstart, cursor, dinv);
  k_scatter<<<(EE + 255) / 256, 256, 0, stream>>>(srcp, dstp, cursor, csr_src);

  const void* Xin = x;
  for (int l = 0; l < LL; ++l) {
    const __half* Wh = Wth + (size_t)l * DD * DD;
    const __half* Wl = Wtl + (size_t)l * DD * DD;
    if (l == 0)
      k_gemm<0><<<(NN + 127) / 128, 512, 0, stream>>>(
          Xin, Wh, Wl, bufB, stats, gammas, betas, dinv);
    else
      k_gemm<1><<<(NN + 127) / 128, 512, 0, stream>>>(
          Xin, Wh, Wl, bufB, stats + (l - 1) * 256, gammas + (l - 1) * DD,
          betas + (l - 1) * DD, dinv);
    k_agg_csr<<<(NN + 3) / 4, 256, 0, stream>>>((const __half2*)bufB, rowstart,
                                                csr_src, dinv, (__half2*)bufA);
    k_bnstats<<<256, 256, 0, stream>>>((const __half2*)bufA, stats + l * 256);
    Xin = bufA;
  }

  k_pool<<<(NN + 127) / 128, 256, 0, stream>>>(bufA, bidx, stats + 2 * 256,
                                               gammas + 2 * DD, betas + 2 * DD,
                                               out, cnts);
  k_div<<<(GGR * DD + 255) / 256, 256, 0, stream>>>(out, cnts);
}